// Round 3
// baseline (285.058 us; speedup 1.0000x reference)
//
#include <hip/hip_runtime.h>

// Problem constants (from reference)
#define KSZ   7
#define KK    49          // K*K
#define GCH   16          // group_channels
#define CIN   256
#define MID   64
#define NGRP  16
#define WID   56
#define HWSZ  3136        // 56*56
#define NB    4
#define NPIX  (NB * HWSZ) // 12544
#define EPSV  1e-5f

// ws layout (floats):
// [0..63]    per-channel sum
// [64..127]  per-channel sumsq
// [128..191] a  (gamma * rsqrt(var+eps))
// [192..255] c  (beta - mu*a)
// [256 ...]  t_pre  [pix][MID]  (transposed: 64 contiguous per pixel)

// 64-thread blocks: 1 wave each, no LDS, no __syncthreads needed.
__global__ __launch_bounds__(64, 4) void k1_conv1(const float* __restrict__ x,
                                                  const float* __restrict__ w1,
                                                  const float* __restrict__ b1,
                                                  float* __restrict__ ws) {
    const int tid = threadIdx.x;
    const int pix = blockIdx.x * 64 + tid;        // 196 blocks * 64 = 12544
    const int ob  = blockIdx.y * 8;               // 8 chunks of 8 mid-channels
    const int b   = pix / HWSZ;
    const int hw  = pix - b * HWSZ;

    float acc[8];
#pragma unroll
    for (int i = 0; i < 8; ++i) acc[i] = b1[ob + i];

    const float* xp = x + (size_t)b * CIN * HWSZ + hw;
#pragma unroll 8
    for (int c = 0; c < CIN; ++c) {
        const float xv = xp[(size_t)c * HWSZ];
#pragma unroll
        for (int i = 0; i < 8; ++i)
            acc[i] = fmaf(w1[(ob + i) * CIN + c], xv, acc[i]);   // uniform -> s_load
    }

    // transposed store: t[pix][64]
    float4* tp = (float4*)(ws + 256 + (size_t)pix * MID + ob);
    tp[0] = make_float4(acc[0], acc[1], acc[2], acc[3]);
    tp[1] = make_float4(acc[4], acc[5], acc[6], acc[7]);

    // batch stats: wave shuffle reduce + lane-0 global atomics
#pragma unroll
    for (int i = 0; i < 8; ++i) {
        float s = acc[i];
        float q = acc[i] * acc[i];
#pragma unroll
        for (int m = 1; m < 64; m <<= 1) {
            s += __shfl_xor(s, m, 64);
            q += __shfl_xor(q, m, 64);
        }
        if (tid == 0) {
            atomicAdd(&ws[ob + i],      s);
            atomicAdd(&ws[64 + ob + i], q);
        }
    }
}

__global__ void k2_stats(float* __restrict__ ws,
                         const float* __restrict__ gamma,
                         const float* __restrict__ beta) {
    const int o = threadIdx.x;  // 64 threads
    const float n   = (float)NPIX;
    const float mu  = ws[o] / n;
    const float var = ws[64 + o] / n - mu * mu;
    const float a   = gamma[o] * rsqrtf(var + EPSV);
    ws[128 + o] = a;
    ws[192 + o] = beta[o] - mu * a;
}

__global__ __launch_bounds__(64, 4) void k3_fused(const float* __restrict__ x,
                                                  const float* __restrict__ w2,
                                                  const float* __restrict__ b2,
                                                  const float* __restrict__ ws,
                                                  float* __restrict__ out) {
    const int tid = threadIdx.x;
    const int pix = blockIdx.x * 64 + tid;        // 196 blocks * 64
    const int g   = blockIdx.y;                   // group, wave-uniform
    const int b   = pix / HWSZ;
    const int hw  = pix - b * HWSZ;
    const int h   = hw / WID;
    const int w   = hw - h * WID;

    // ---------- Phase A: per-pixel kernel weights wgt[49] ----------
    // Never hold all 64 t-values: chunk mid-channels by 8 so live set is
    // tv[8] + wgt[49] (~70 VGPR).
    float wgt[KK];
    const float* w2g = w2 + (size_t)g * KK * MID;
    const float* b2g = b2 + (size_t)g * KK;
#pragma unroll
    for (int k = 0; k < KK; ++k) wgt[k] = b2g[k];

    const float* tb = ws + 256 + (size_t)pix * MID;
    for (int oc = 0; oc < MID; oc += 8) {
        const float4 v0 = *(const float4*)(tb + oc);
        const float4 v1 = *(const float4*)(tb + oc + 4);
        float tv[8];
        tv[0] = fmaxf(0.f, fmaf(ws[128 + oc + 0], v0.x, ws[192 + oc + 0]));
        tv[1] = fmaxf(0.f, fmaf(ws[128 + oc + 1], v0.y, ws[192 + oc + 1]));
        tv[2] = fmaxf(0.f, fmaf(ws[128 + oc + 2], v0.z, ws[192 + oc + 2]));
        tv[3] = fmaxf(0.f, fmaf(ws[128 + oc + 3], v0.w, ws[192 + oc + 3]));
        tv[4] = fmaxf(0.f, fmaf(ws[128 + oc + 4], v1.x, ws[192 + oc + 4]));
        tv[5] = fmaxf(0.f, fmaf(ws[128 + oc + 5], v1.y, ws[192 + oc + 5]));
        tv[6] = fmaxf(0.f, fmaf(ws[128 + oc + 6], v1.z, ws[192 + oc + 6]));
        tv[7] = fmaxf(0.f, fmaf(ws[128 + oc + 7], v1.w, ws[192 + oc + 7]));
#pragma unroll
        for (int k = 0; k < KK; ++k) {
#pragma unroll
            for (int o = 0; o < 8; ++o)
                wgt[k] = fmaf(w2g[k * MID + oc + o], tv[o], wgt[k]);  // uniform
        }
    }

    // ---------- Phase B: involution (weighted 7x7 gather) ----------
    float acc[GCH];
#pragma unroll
    for (int cc = 0; cc < GCH; ++cc) acc[cc] = 0.f;

    const float* xg = x + ((size_t)b * CIN + (size_t)g * GCH) * HWSZ;

#pragma unroll
    for (int k = 0; k < KK; ++k) {
        const int di = k / 7 - 3;
        const int dj = k % 7 - 3;
        const int hh  = h + di;
        const int wwv = w + dj;
        const bool valid = ((unsigned)hh < 56u) && ((unsigned)wwv < 56u);
        const float wm = valid ? wgt[k] : 0.f;
        const float* xb = xg + (valid ? hh * WID + wwv : 0);
#pragma unroll
        for (int cc = 0; cc < GCH; ++cc)
            acc[cc] = fmaf(wm, xb[(size_t)cc * HWSZ], acc[cc]);
    }

    float* ob = out + ((size_t)b * CIN + (size_t)g * GCH) * HWSZ + hw;
#pragma unroll
    for (int cc = 0; cc < GCH; ++cc) ob[(size_t)cc * HWSZ] = acc[cc];
}

extern "C" void kernel_launch(void* const* d_in, const int* in_sizes, int n_in,
                              void* d_out, int out_size, void* d_ws, size_t ws_size,
                              hipStream_t stream) {
    const float* x     = (const float*)d_in[0];
    const float* w1    = (const float*)d_in[1];
    const float* b1    = (const float*)d_in[2];
    const float* gamma = (const float*)d_in[3];
    const float* beta  = (const float*)d_in[4];
    const float* w2    = (const float*)d_in[5];
    const float* b2    = (const float*)d_in[6];
    float* out = (float*)d_out;
    float* ws  = (float*)d_ws;

    // zero the stats accumulators (first 128 floats)
    hipMemsetAsync(ws, 0, 128 * sizeof(float), stream);

    k1_conv1<<<dim3(196, 8), 64, 0, stream>>>(x, w1, b1, ws);
    k2_stats<<<1, 64, 0, stream>>>(ws, gamma, beta);
    k3_fused<<<dim3(196, 16), 64, 0, stream>>>(x, w2, b2, ws, out);
}